// Round 12
// baseline (291.117 us; speedup 1.0000x reference)
//
#include <hip/hip_runtime.h>
#include <hip/hip_bf16.h>

using bf16 = __hip_bfloat16;
typedef __bf16 bf16v8 __attribute__((ext_vector_type(8)));
typedef float f32x4 __attribute__((ext_vector_type(4)));

#define HW 4096      // 64*64 spatial per image
#define ROWS 65536   // 16*HW
#define BRSTRIDE 4194304   // 8 MiB bf16 elems per branch tensor (q)

#define AS1 const __attribute__((address_space(1))) void*
#define AS3 __attribute__((address_space(3))) void*

// ------- convert 6 weight matrices + pack Wb1 + zero stats (one launch) ------
__global__ void r4_cvt_w(const float* __restrict__ Wsc, const float* __restrict__ W1,
                         const float* __restrict__ Wb0,
                         const float* __restrict__ Wqkv2, const float* __restrict__ Wqkv3,
                         const float* __restrict__ W2, const float* __restrict__ Wb1,
                         bf16* __restrict__ wbase, bf16* __restrict__ wp,
                         float* __restrict__ stats) {
    int i = blockIdx.x * 256 + threadIdx.x;   // 768 blocks * 256 = 196608
    if (i < 2048) stats[i] = 0.f;
    if (i < 159744) {
        const float* s; int off;
        if      (i < 32768)  { s = Wsc;   off = i; }
        else if (i < 65536)  { s = W1;    off = i - 32768; }
        else if (i < 69632)  { s = Wb0;   off = i - 65536; }
        else if (i < 81920)  { s = Wqkv2; off = i - 69632; }
        else if (i < 94208)  { s = Wqkv3; off = i - 81920; }
        else                 { s = W2;    off = i - 94208; }
        wbase[i] = __float2bfloat16(s[off]);
    } else {
        int k = i - 159744;                  // 0..36863: Wb1 [o][c][3][3] -> [tap][o][c]
        int tap = k / 4096, rem = k % 4096;
        int o = rem >> 6, c = rem & 63;
        wp[k] = __float2bfloat16(Wb1[(size_t)(o * 64 + c) * 9 + tap]);
    }
}

// ------- convert+transpose x: fp32 [b][c=128][n] -> bf16 [b][n][c=128] -------
__global__ void r4_cvt_x(const float* __restrict__ x, bf16* __restrict__ xT) {
    __shared__ bf16 tile[64 * 65];
    int b = blockIdx.z, c0 = blockIdx.y * 64, n0 = blockIdx.x * 64;
    int t = threadIdx.x;
#pragma unroll
    for (int i = 0; i < 4; i++) {
        int idx = i * 256 + t;
        int cc = idx >> 4, n4 = (idx & 15) * 4;
        float4 v = *(const float4*)&x[((size_t)(b * 128 + c0 + cc)) * HW + n0 + n4];
        tile[(n4 + 0) * 65 + cc] = __float2bfloat16(v.x);
        tile[(n4 + 1) * 65 + cc] = __float2bfloat16(v.y);
        tile[(n4 + 2) * 65 + cc] = __float2bfloat16(v.z);
        tile[(n4 + 3) * 65 + cc] = __float2bfloat16(v.w);
    }
    __syncthreads();
#pragma unroll
    for (int i = 0; i < 2; i++) {
        int u = i * 256 + t;
        int nn = u >> 3, p = u & 7;
        bf16v8 v;
#pragma unroll
        for (int j = 0; j < 8; j++) v[j] = (__bf16)tile[nn * 65 + p * 8 + j];
        *(bf16v8*)&xT[((size_t)(b * HW + n0 + nn)) * 128 + c0 + p * 8] = v;
    }
}

// ===== ga_gemm: 128x128 tile, 4 waves (2x2), 64x64 per wave ==================
// K staged in 64-wide phases. Optional in-LDS bn+relu on A (tsums != nullptr).
template <int KK>
__global__ __launch_bounds__(256) void ga_gemm(
        const bf16* __restrict__ A, int a_stride,
        const bf16* __restrict__ W, int w_stride,
        bf16* __restrict__ out0, bf16* __restrict__ out1, int split,
        int out_stride,
        float* __restrict__ stat0, float* __restrict__ stat1,
        int scol0, int scol1,
        const float* __restrict__ tsums,
        const float* __restrict__ tg0, const float* __restrict__ tb0,
        const float* __restrict__ tg1, const float* __restrict__ tb1,
        const float* __restrict__ tg2, const float* __restrict__ tb2,
        const float* __restrict__ tg3, const float* __restrict__ tb3) {
    __shared__ bf16 shmem[128 * 136];
    __shared__ float sredS[256], sredQ[256];
    __shared__ float scS[256], shS[256];
    bf16* As = shmem;                     // [128][64]
    bf16* Ws = shmem + 8192;              // [128][64]

    int t = threadIdx.x;
    int wave = t >> 6, lane = t & 63;
    int lo = lane & 15, quad = lane >> 4;
    int wr = wave >> 1, wc = wave & 1;
    int b = blockIdx.z;
    long grow = (long)b * HW + blockIdx.x * 128;
    int o0 = blockIdx.y * 128;
    const bf16* Wb = W + (long)o0 * w_stride;

    if (tsums) {   // quarter-concat bn params for the 256 input channels
        int qi = t >> 6, ci = t & 63;
        const float* gp = qi == 0 ? tg0 : qi == 1 ? tg1 : qi == 2 ? tg2 : tg3;
        const float* bp = qi == 0 ? tb0 : qi == 1 ? tb1 : qi == 2 ? tb2 : tb3;
        float mean = tsums[t] * (1.f / 65536.f);
        float var  = tsums[256 + t] * (1.f / 65536.f) - mean * mean;
        float s = gp[ci] * rsqrtf(var + 1e-5f);
        scS[t] = s; shS[t] = bp[ci] - mean * s;
    }

    f32x4 acc[4][4];
#pragma unroll
    for (int m = 0; m < 4; m++)
#pragma unroll
        for (int n = 0; n < 4; n++) acc[m][n] = (f32x4){0.f, 0.f, 0.f, 0.f};

#pragma unroll
    for (int ph = 0; ph < KK / 64; ph++) {
        int k0 = ph * 64;
#pragma unroll
        for (int j = 0; j < 4; j++) {
            int i = j * 4 + wave;
            int ci = i * 64 + lane;
            int R = ci >> 3, cc = ci & 7;
            int sw = ((cc ^ (R & 7)) << 3);
            __builtin_amdgcn_global_load_lds(
                (AS1)(A + (grow + R) * (long)a_stride + k0 + sw),
                (AS3)(As + i * 512), 16, 0, 0);
            __builtin_amdgcn_global_load_lds(
                (AS1)(Wb + (long)R * w_stride + k0 + sw),
                (AS3)(Ws + i * 512), 16, 0, 0);
        }
        asm volatile("s_waitcnt vmcnt(0)" ::: "memory");
        __syncthreads();
        if (tsums) {   // bn+relu the staged A tile in LDS
#pragma unroll
            for (int i = 0; i < 4; i++) {
                int ci = i * 256 + t;
                int R = ci >> 3, p = ci & 7;
                int chb = k0 + ((p ^ (R & 7)) << 3);
                bf16v8 v = *(const bf16v8*)&As[R * 64 + p * 8];
#pragma unroll
                for (int j = 0; j < 8; j++) {
                    float f = (float)v[j] * scS[chb + j] + shS[chb + j];
                    v[j] = (__bf16)fmaxf(f, 0.f);
                }
                *(bf16v8*)&As[R * 64 + p * 8] = v;
            }
            __syncthreads();
        }
#pragma unroll
        for (int ks = 0; ks < 64; ks += 32) {
            int kk = (ks >> 3) + quad;
            bf16v8 av[4], wv[4];
#pragma unroll
            for (int m = 0; m < 4; m++) {
                int R = wr * 64 + m * 16 + lo;
                av[m] = *(const bf16v8*)&As[R * 64 + ((kk ^ (R & 7)) << 3)];
            }
#pragma unroll
            for (int n = 0; n < 4; n++) {
                int R = wc * 64 + n * 16 + lo;
                wv[n] = *(const bf16v8*)&Ws[R * 64 + ((kk ^ (R & 7)) << 3)];
            }
#pragma unroll
            for (int m = 0; m < 4; m++)
#pragma unroll
                for (int n = 0; n < 4; n++)
                    acc[m][n] = __builtin_amdgcn_mfma_f32_16x16x32_bf16(av[m], wv[n], acc[m][n], 0, 0, 0);
        }
        __syncthreads();
    }

    bf16* Ot = shmem;
#pragma unroll
    for (int m = 0; m < 4; m++)
#pragma unroll
        for (int n = 0; n < 4; n++)
#pragma unroll
            for (int r = 0; r < 4; r++)
                Ot[(wr * 64 + m * 16 + quad * 4 + r) * 136 + wc * 64 + n * 16 + lo] =
                    __float2bfloat16(acc[m][n][r]);
    __syncthreads();
    bool low = o0 < split;
    bf16* op = low ? out0 : out1;
    int oc0 = low ? o0 : o0 - split;
#pragma unroll
    for (int i = 0; i < 8; i++) {
        int u = i * 256 + t;
        int lr = u >> 4, cg = u & 15;
        *(bf16v8*)&op[(grow + lr) * (long)out_stride + oc0 + cg * 8] =
            *(const bf16v8*)&Ot[lr * 136 + cg * 8];
    }
    if (stat0) {
        int c = t & 127, half = t >> 7;
        float s = 0.f, q = 0.f;
#pragma unroll
        for (int r = 0; r < 64; r++) {
            float v = __bfloat162float(Ot[(half * 64 + r) * 136 + c]);
            s += v; q += v * v;
        }
        sredS[t] = s; sredQ[t] = q;
        __syncthreads();
        if (t < 128) {
            float ss = sredS[t] + sredS[t + 128];
            float qq = sredQ[t] + sredQ[t + 128];
            float* st = low ? stat0 : stat1;
            int ci = (low ? scol0 + o0 : scol1 + o0 - split) + c;
            atomicAdd(&st[ci], ss);
            atomicAdd(&st[256 + ci], qq);
        }
    }
}

// ===== gq_gemm: 128x64 tile, K=64. q (both branches) + branch0 ===============
// grid (32, 3, 16): y=0,1 -> q of branch y; y=2 -> branch0 1x1.
__global__ __launch_bounds__(256) void gq_gemm(
        const bf16* __restrict__ y1,
        const bf16* __restrict__ wq2, const bf16* __restrict__ wq3,
        const bf16* __restrict__ wb0,
        bf16* __restrict__ qs,
        bf16* __restrict__ obuf, float* __restrict__ stats,
        const float* __restrict__ asums,
        const float* __restrict__ g1, const float* __restrict__ b1) {
    __shared__ bf16 shmem[128 * 64 + 64 * 64];   // 24576 B
    __shared__ float scS[64], shS[64];
    bf16* As = shmem;                    // [128][64]
    bf16* Ws = shmem + 8192;             // [64][64]
    float* sredS = (float*)(shmem + 9216);   // byte 18432, after Ot
    float* sredQ = sredS + 256;

    int t = threadIdx.x;
    int wave = t >> 6, lane = t & 63;
    int lo = lane & 15, quad = lane >> 4;
    int b = blockIdx.z, y = blockIdx.y;
    long grow = (long)b * HW + blockIdx.x * 128;

    const bf16* Ab; const bf16* Wb; bf16* outp; int ostride; float* st; int col0;
    if (y == 2) {
        Ab = y1; Wb = wb0; outp = obuf; ostride = 256; st = stats; col0 = 0;
    } else {
        col0 = 128 + y * 64;
        Ab = y1 + col0;
        Wb = (y ? wq3 : wq2);            // sel 0 = q
        outp = qs + (long)y * BRSTRIDE;
        ostride = 64; st = nullptr;
    }
    if (t < 64) {
        int ch = col0 + t;
        float mean = asums[ch] * (1.f / 65536.f);
        float var  = asums[256 + ch] * (1.f / 65536.f) - mean * mean;
        float s = g1[ch] * rsqrtf(var + 1e-5f);
        scS[t] = s; shS[t] = b1[ch] - mean * s;
    }

    f32x4 acc[2][4];
#pragma unroll
    for (int m = 0; m < 2; m++)
#pragma unroll
        for (int n = 0; n < 4; n++) acc[m][n] = (f32x4){0.f, 0.f, 0.f, 0.f};

#pragma unroll
    for (int j = 0; j < 4; j++) {          // A: 128 rows x 8 chunks = 1024
        int i = j * 4 + wave;
        int ci = i * 64 + lane;
        int R = ci >> 3, cc = ci & 7;
        __builtin_amdgcn_global_load_lds(
            (AS1)(Ab + (grow + R) * 256L + ((cc ^ (R & 7)) << 3)),
            (AS3)(As + i * 512), 16, 0, 0);
    }
#pragma unroll
    for (int j = 0; j < 2; j++) {          // W: 64 rows x 8 chunks = 512
        int ci = (j * 4 + wave) * 64 + lane;
        int R = ci >> 3, cc = ci & 7;
        __builtin_amdgcn_global_load_lds(
            (AS1)(Wb + R * 64 + ((cc ^ (R & 7)) << 3)),
            (AS3)(Ws + (j * 4 + wave) * 512), 16, 0, 0);
    }
    asm volatile("s_waitcnt vmcnt(0)" ::: "memory");
    __syncthreads();
    // bn+relu the staged A tile in LDS (raw y1 -> h)
#pragma unroll
    for (int i = 0; i < 4; i++) {
        int ci = i * 256 + t;
        int R = ci >> 3, p = ci & 7;
        int chb = (p ^ (R & 7)) << 3;
        bf16v8 v = *(const bf16v8*)&As[R * 64 + p * 8];
#pragma unroll
        for (int j = 0; j < 8; j++) {
            float f = (float)v[j] * scS[chb + j] + shS[chb + j];
            v[j] = (__bf16)fmaxf(f, 0.f);
        }
        *(bf16v8*)&As[R * 64 + p * 8] = v;
    }
    __syncthreads();

#pragma unroll
    for (int ks_ = 0; ks_ < 64; ks_ += 32) {
        int kk = (ks_ >> 3) + quad;
        bf16v8 av[2], wv[4];
#pragma unroll
        for (int m = 0; m < 2; m++) {
            int R = wave * 32 + m * 16 + lo;
            av[m] = *(const bf16v8*)&As[R * 64 + ((kk ^ (R & 7)) << 3)];
        }
#pragma unroll
        for (int n = 0; n < 4; n++) {
            int o = n * 16 + lo;
            wv[n] = *(const bf16v8*)&Ws[o * 64 + ((kk ^ (o & 7)) << 3)];
        }
#pragma unroll
        for (int m = 0; m < 2; m++)
#pragma unroll
            for (int n = 0; n < 4; n++)
                acc[m][n] = __builtin_amdgcn_mfma_f32_16x16x32_bf16(av[m], wv[n], acc[m][n], 0, 0, 0);
    }
    __syncthreads();

    bf16* Ot = shmem;                       // [128][72] = 18432 B
#pragma unroll
    for (int m = 0; m < 2; m++)
#pragma unroll
        for (int n = 0; n < 4; n++)
#pragma unroll
            for (int r = 0; r < 4; r++)
                Ot[(wave * 32 + m * 16 + quad * 4 + r) * 72 + n * 16 + lo] =
                    __float2bfloat16(acc[m][n][r]);
    __syncthreads();
#pragma unroll
    for (int i = 0; i < 4; i++) {
        int u = i * 256 + t;
        int lr = u >> 3, cg = u & 7;
        *(bf16v8*)&outp[(grow + lr) * (long)ostride + cg * 8] =
            *(const bf16v8*)&Ot[lr * 72 + cg * 8];
    }
    if (st) {
        int c = t & 63, qtr = t >> 6;
        float s = 0.f, q = 0.f;
#pragma unroll
        for (int r = 0; r < 32; r++) {
            float v = __bfloat162float(Ot[(qtr * 32 + r) * 72 + c]);
            s += v; q += v * v;
        }
        sredS[t] = s; sredQ[t] = q;
        __syncthreads();
        if (t < 64) {
            float ss = sredS[t] + sredS[t + 64] + sredS[t + 128] + sredS[t + 192];
            float qq = sredQ[t] + sredQ[t + 64] + sredQ[t + 128] + sredQ[t + 192];
            atomicAdd(&st[t], ss);
            atomicAdd(&st[256 + t], qq);
        }
    }
}

// ===== gkv_ctx: fused k,v gemms + exp + transpose + ctx partial ==============
// grid (32, 2, 16): bx = 128-row n-chunk, y = branch, z = batch. No k/v in HBM.
// ctx_p[br][b][bx][c][d] (fp32), lpart[br][b][bx][c].
__global__ __launch_bounds__(256) void gkv_ctx(
        const bf16* __restrict__ y1,
        const bf16* __restrict__ wq2, const bf16* __restrict__ wq3,
        float* __restrict__ ctx_p, float* __restrict__ lpart,
        const float* __restrict__ asums,
        const float* __restrict__ g1, const float* __restrict__ b1) {
    __shared__ bf16 As[128 * 64];        // 16384 B (h tile; aliased by red later)
    __shared__ bf16 Ws[2 * 64 * 64];     // 16384 B (Wk | Wv)
    __shared__ bf16 Kt[64 * 136];        // 17408 B exp(k) transposed [c][n]
    __shared__ bf16 Vt[64 * 136];        // 17408 B v transposed [d][n]
    __shared__ float scS[64], shS[64];
    float* red = (float*)As;             // 16x64 f, reused after k/v MFMAs

    int t = threadIdx.x;
    int wave = t >> 6, lane = t & 63;
    int lo = lane & 15, quad = lane >> 4;
    int b = blockIdx.z, br = blockIdx.y, bx = blockIdx.x;
    long grow = (long)b * HW + bx * 128;
    int col0 = 128 + br * 64;
    const bf16* Ab = y1 + col0;
    const bf16* Wk = (br ? wq3 : wq2) + 4096;       // sel 1 = k
    const bf16* Wv = (br ? wq3 : wq2) + 8192;       // sel 2 = v

    if (t < 64) {
        int ch = col0 + t;
        float mean = asums[ch] * (1.f / 65536.f);
        float var  = asums[256 + ch] * (1.f / 65536.f) - mean * mean;
        float s = g1[ch] * rsqrtf(var + 1e-5f);
        scS[t] = s; shS[t] = b1[ch] - mean * s;
    }

#pragma unroll
    for (int j = 0; j < 4; j++) {          // A: 128 rows x 8 chunks
        int i = j * 4 + wave;
        int ci = i * 64 + lane;
        int R = ci >> 3, cc = ci & 7;
        __builtin_amdgcn_global_load_lds(
            (AS1)(Ab + (grow + R) * 256L + ((cc ^ (R & 7)) << 3)),
            (AS3)(As + i * 512), 16, 0, 0);
    }
#pragma unroll
    for (int j = 0; j < 2; j++) {          // Wk
        int ci = (j * 4 + wave) * 64 + lane;
        int R = ci >> 3, cc = ci & 7;
        __builtin_amdgcn_global_load_lds(
            (AS1)(Wk + R * 64 + ((cc ^ (R & 7)) << 3)),
            (AS3)(Ws + (j * 4 + wave) * 512), 16, 0, 0);
    }
#pragma unroll
    for (int j = 0; j < 2; j++) {          // Wv
        int ci = (j * 4 + wave) * 64 + lane;
        int R = ci >> 3, cc = ci & 7;
        __builtin_amdgcn_global_load_lds(
            (AS1)(Wv + R * 64 + ((cc ^ (R & 7)) << 3)),
            (AS3)(Ws + 4096 + (j * 4 + wave) * 512), 16, 0, 0);
    }
    asm volatile("s_waitcnt vmcnt(0)" ::: "memory");
    __syncthreads();
    // bn+relu staged h tile
#pragma unroll
    for (int i = 0; i < 4; i++) {
        int ci = i * 256 + t;
        int R = ci >> 3, p = ci & 7;
        int chb = (p ^ (R & 7)) << 3;
        bf16v8 v = *(const bf16v8*)&As[R * 64 + p * 8];
#pragma unroll
        for (int j = 0; j < 8; j++) {
            float f = (float)v[j] * scS[chb + j] + shS[chb + j];
            v[j] = (__bf16)fmaxf(f, 0.f);
        }
        *(bf16v8*)&As[R * 64 + p * 8] = v;
    }
    __syncthreads();

    // k and v GEMMs (rows 128, out 64, K=64)
    f32x4 aK[2][4], aV[2][4];
#pragma unroll
    for (int m = 0; m < 2; m++)
#pragma unroll
        for (int n = 0; n < 4; n++) {
            aK[m][n] = (f32x4){0.f, 0.f, 0.f, 0.f};
            aV[m][n] = (f32x4){0.f, 0.f, 0.f, 0.f};
        }
#pragma unroll
    for (int ks_ = 0; ks_ < 64; ks_ += 32) {
        int kk = (ks_ >> 3) + quad;
        bf16v8 av[2], wk[4], wv[4];
#pragma unroll
        for (int m = 0; m < 2; m++) {
            int R = wave * 32 + m * 16 + lo;
            av[m] = *(const bf16v8*)&As[R * 64 + ((kk ^ (R & 7)) << 3)];
        }
#pragma unroll
        for (int n = 0; n < 4; n++) {
            int o = n * 16 + lo;
            wk[n] = *(const bf16v8*)&Ws[o * 64 + ((kk ^ (o & 7)) << 3)];
            wv[n] = *(const bf16v8*)&Ws[4096 + o * 64 + ((kk ^ (o & 7)) << 3)];
        }
#pragma unroll
        for (int m = 0; m < 2; m++)
#pragma unroll
            for (int n = 0; n < 4; n++) {
                aK[m][n] = __builtin_amdgcn_mfma_f32_16x16x32_bf16(av[m], wk[n], aK[m][n], 0, 0, 0);
                aV[m][n] = __builtin_amdgcn_mfma_f32_16x16x32_bf16(av[m], wv[n], aV[m][n], 0, 0, 0);
            }
    }
    __syncthreads();   // all As/Ws reads done (red aliases As)

    // exp(k) fp32 -> transposed LDS; v -> transposed LDS; per-lane l partials
    float sm[4] = {0.f, 0.f, 0.f, 0.f};
#pragma unroll
    for (int m = 0; m < 2; m++)
#pragma unroll
        for (int n = 0; n < 4; n++)
#pragma unroll
            for (int r = 0; r < 4; r++) {
                int row = wave * 32 + m * 16 + quad * 4 + r;   // n-dim
                int col = n * 16 + lo;                         // c-dim
                float e = expf(aK[m][n][r]);
                sm[n] += e;
                Kt[col * 136 + row] = __float2bfloat16(e);
                Vt[col * 136 + row] = __float2bfloat16(aV[m][n][r]);
            }
    {
        int g = wave * 4 + quad;
#pragma unroll
        for (int n = 0; n < 4; n++) red[g * 64 + n * 16 + lo] = sm[n];
    }
    __syncthreads();

    // ctx MFMA: ctx[c][d] = sum_n Kt[c][n] * Vt[d][n]
    f32x4 acc[4];
#pragma unroll
    for (int ot = 0; ot < 4; ot++) acc[ot] = (f32x4){0.f, 0.f, 0.f, 0.f};
#pragma unroll
    for (int ks_ = 0; ks_ < 128; ks_ += 32) {
        bf16v8 av = *(const bf16v8*)&Kt[(wave * 16 + lo) * 136 + ks_ + quad * 8];
#pragma unroll
        for (int ot = 0; ot < 4; ot++) {
            bf16v8 bv = *(const bf16v8*)&Vt[(ot * 16 + lo) * 136 + ks_ + quad * 8];
            acc[ot] = __builtin_amdgcn_mfma_f32_16x16x32_bf16(av, bv, acc[ot], 0, 0, 0);
        }
    }
    long blk = ((long)br * 16 + b) * 32 + bx;
#pragma unroll
    for (int ot = 0; ot < 4; ot++) {
#pragma unroll
        for (int r = 0; r < 4; r++) {
            int c = wave * 16 + quad * 4 + r;
            int d = ot * 16 + lo;
            ctx_p[(blk * 64 + c) * 64 + d] = acc[ot][r];
        }
    }
    if (t < 64) {
        float l = 0.f;
#pragma unroll
        for (int g = 0; g < 16; g++) l += red[g * 64 + t];
        lpart[blk * 64 + t] = l;
    }
}

// ===== gp_gemm: PV, 128x64 tile. grid (32, 2, 16), y = branch ================
__global__ __launch_bounds__(256) void gp_gemm(
        const bf16* __restrict__ qs, const bf16* __restrict__ M,
        bf16* __restrict__ obuf, float* __restrict__ stats) {
    __shared__ bf16 shmem[128 * 64 + 64 * 64];   // 24576 B
    bf16* As = shmem;
    bf16* Ws = shmem + 8192;
    float* sredS = (float*)(shmem + 9216);
    float* sredQ = sredS + 256;

    int t = threadIdx.x;
    int wave = t >> 6, lane = t & 63;
    int lo = lane & 15, quad = lane >> 4;
    int b = blockIdx.z, y = blockIdx.y;
    long grow = (long)b * HW + blockIdx.x * 128;
    const bf16* Ab = qs + (long)y * BRSTRIDE;
    const bf16* Wb = M + y * 65536 + (long)b * 4096;
    int oc0 = 128 + y * 64;

    f32x4 acc[2][4];
#pragma unroll
    for (int m = 0; m < 2; m++)
#pragma unroll
        for (int n = 0; n < 4; n++) acc[m][n] = (f32x4){0.f, 0.f, 0.f, 0.f};

#pragma unroll
    for (int j = 0; j < 4; j++) {          // A: 128 rows x 8 chunks (stride 64)
        int i = j * 4 + wave;
        int ci = i * 64 + lane;
        int R = ci >> 3, cc = ci & 7;
        __builtin_amdgcn_global_load_lds(
            (AS1)(Ab + (grow + R) * 64L + ((cc ^ (R & 7)) << 3)),
            (AS3)(As + i * 512), 16, 0, 0);
    }
#pragma unroll
    for (int j = 0; j < 2; j++) {          // W: 64 rows x 8 chunks
        int ci = (j * 4 + wave) * 64 + lane;
        int R = ci >> 3, cc = ci & 7;
        __builtin_amdgcn_global_load_lds(
            (AS1)(Wb + R * 64 + ((cc ^ (R & 7)) << 3)),
            (AS3)(Ws + (j * 4 + wave) * 512), 16, 0, 0);
    }
    asm volatile("s_waitcnt vmcnt(0)" ::: "memory");
    __syncthreads();

#pragma unroll
    for (int ks_ = 0; ks_ < 64; ks_ += 32) {
        int kk = (ks_ >> 3) + quad;
        bf16v8 av[2], wv[4];
#pragma unroll
        for (int m = 0; m < 2; m++) {
            int R = wave * 32 + m * 16 + lo;
            av[m] = *(const bf16v8*)&As[R * 64 + ((kk ^ (R & 7)) << 3)];
        }
#pragma unroll
        for (int n = 0; n < 4; n++) {
            int o = n * 16 + lo;
            wv[n] = *(const bf16v8*)&Ws[o * 64 + ((kk ^ (o & 7)) << 3)];
        }
#pragma unroll
        for (int m = 0; m < 2; m++)
#pragma unroll
            for (int n = 0; n < 4; n++)
                acc[m][n] = __builtin_amdgcn_mfma_f32_16x16x32_bf16(av[m], wv[n], acc[m][n], 0, 0, 0);
    }
    __syncthreads();

    bf16* Ot = shmem;                       // [128][72]
#pragma unroll
    for (int m = 0; m < 2; m++)
#pragma unroll
        for (int n = 0; n < 4; n++)
#pragma unroll
            for (int r = 0; r < 4; r++)
                Ot[(wave * 32 + m * 16 + quad * 4 + r) * 72 + n * 16 + lo] =
                    __float2bfloat16(acc[m][n][r]);
    __syncthreads();
#pragma unroll
    for (int i = 0; i < 4; i++) {
        int u = i * 256 + t;
        int lr = u >> 3, cg = u & 7;
        *(bf16v8*)&obuf[(grow + lr) * 256L + oc0 + cg * 8] =
            *(const bf16v8*)&Ot[lr * 72 + cg * 8];
    }
    {
        int c = t & 63, qtr = t >> 6;
        float s = 0.f, q = 0.f;
#pragma unroll
        for (int r = 0; r < 32; r++) {
            float v = __bfloat162float(Ot[(qtr * 32 + r) * 72 + c]);
            s += v; q += v * v;
        }
        sredS[t] = s; sredQ[t] = q;
        __syncthreads();
        if (t < 64) {
            float ss = sredS[t] + sredS[t + 64] + sredS[t + 128] + sredS[t + 192];
            float qq = sredQ[t] + sredQ[t + 64] + sredQ[t + 128] + sredQ[t + 192];
            atomicAdd(&stats[oc0 + t], ss);
            atomicAdd(&stats[256 + oc0 + t], qq);
        }
    }
}

// ===== r12 conv3: 4 y-rows/block; raw y1 staged, bn+relu in LDS ==============
__global__ __launch_bounds__(256) void r12_conv3(
        const bf16* __restrict__ hT, const bf16* __restrict__ wp,
        bf16* __restrict__ obuf, float* __restrict__ stat,
        const float* __restrict__ asums,
        const float* __restrict__ g1, const float* __restrict__ b1) {
    __shared__ bf16 As[6 * 66 * 64];
    __shared__ bf16 Wt[9 * 64 * 64];
    __shared__ float sredS[256], sredQ[256];
    __shared__ float scS[64], shS[64];

    int t = threadIdx.x;
    int wave = t >> 6, lane = t & 63;
    int lo = lane & 15, quad = lane >> 4;
    int b = blockIdx.y, y0 = blockIdx.x * 4;

    if (t < 64) {   // channels 64..127 of y1
        int ch = 64 + t;
        float mean = asums[ch] * (1.f / 65536.f);
        float var  = asums[256 + ch] * (1.f / 65536.f) - mean * mean;
        float s = g1[ch] * rsqrtf(var + 1e-5f);
        scS[t] = s; shS[t] = b1[ch] - mean * s;
    }

#pragma unroll
    for (int j = 0; j < 18; j++) {
        int i = j * 4 + wave;
        int ci = i * 64 + lane;
        int tap = ci >> 9, rem = ci & 511, o = rem >> 3, ck = rem & 7;
        __builtin_amdgcn_global_load_lds(
            (AS1)(wp + tap * 4096 + o * 64 + ((ck ^ (o & 7)) << 3)),
            (AS3)(Wt + i * 512), 16, 0, 0);
    }
#pragma unroll
    for (int j = 0; j < 12; j++) {
        int i = j * 4 + wave;            // 0..47
        int row = i >> 3, seg = i & 7;
        int yy = y0 - 1 + row;
        if (yy >= 0 && yy < 64) {
            int xg = seg * 8 + (lane >> 3), ck = lane & 7;
            __builtin_amdgcn_global_load_lds(
                (AS1)(hT + ((long)b * HW + yy * 64 + xg) * 256 + 64 + ((ck ^ (xg & 7)) << 3)),
                (AS3)(As + row * 4224 + 64 + seg * 512), 16, 0, 0);
        } else {
            *(bf16v8*)&As[row * 4224 + 64 + seg * 512 + lane * 8] = (bf16v8){0,0,0,0,0,0,0,0};
        }
    }
    if (t < 96) {
        int yr = t >> 4, side = (t >> 3) & 1, ck = t & 7;
        *(bf16v8*)&As[yr * 4224 + (side ? 65 : 0) * 64 + ck * 8] = (bf16v8){0,0,0,0,0,0,0,0};
    }
    asm volatile("s_waitcnt vmcnt(0)" ::: "memory");
    __syncthreads();
    // bn+relu valid region only (padding stays zero = pad-after-activation)
#pragma unroll
    for (int i = 0; i < 12; i++) {
        int ci = i * 256 + t;            // 3072 chunks: [row 6][x 64][p 8]
        int row = ci >> 9, rem = ci & 511;
        int xg = rem >> 3, p = rem & 7;
        int yy = y0 - 1 + row;
        if (yy >= 0 && yy < 64) {
            int chb = (p ^ (xg & 7)) << 3;
            bf16v8 v = *(const bf16v8*)&As[row * 4224 + (xg + 1) * 64 + p * 8];
#pragma unroll
            for (int j = 0; j < 8; j++) {
                float f = (float)v[j] * scS[chb + j] + shS[chb + j];
                v[j] = (__bf16)fmaxf(f, 0.f);
            }
            *(bf16v8*)&As[row * 4224 + (xg + 1) * 64 + p * 8] = v;
        }
    }
    __syncthreads();

    f32x4 acc[4][4];   // [m spatial 16][ot out 16]
#pragma unroll
    for (int m = 0; m < 4; m++)
#pragma unroll
        for (int n = 0; n < 4; n++) acc[m][n] = (f32x4){0.f, 0.f, 0.f, 0.f};

#pragma unroll
    for (int tap = 0; tap < 9; tap++) {
        int dy = tap / 3 - 1, dx = tap % 3 - 1;
        int yr = wave + 1 + dy;
#pragma unroll
        for (int ks8 = 0; ks8 < 8; ks8 += 4) {
            int kk = ks8 + quad;
            bf16v8 wv[4];
#pragma unroll
            for (int ot = 0; ot < 4; ot++) {
                int o = ot * 16 + lo;
                wv[ot] = *(const bf16v8*)&Wt[tap * 4096 + o * 64 + ((kk ^ (o & 7)) << 3)];
            }
#pragma unroll
            for (int m = 0; m < 4; m++) {
                int xp = m * 16 + lo + dx;
                bf16v8 av = *(const bf16v8*)&As[yr * 4224 + (xp + 1) * 64 + ((kk ^ (xp & 7)) << 3)];
#pragma unroll
                for (int ot = 0; ot < 4; ot++)
                    acc[m][ot] = __builtin_amdgcn_mfma_f32_16x16x32_bf16(av, wv[ot], acc[m][ot], 0, 0, 0);
            }
        }
    }
    __syncthreads();

    bf16* Ot = As;                        // [256][72]
#pragma unroll
    for (int m = 0; m < 4; m++)
#pragma unroll
        for (int ot = 0; ot < 4; ot++)
#pragma unroll
            for (int r = 0; r < 4; r++)
                Ot[(wave * 64 + m * 16 + quad * 4 + r) * 72 + ot * 16 + lo] =
                    __float2bfloat16(acc[m][ot][r]);
    __syncthreads();

    long grow = (long)b * HW + y0 * 64;
#pragma unroll
    for (int i = 0; i < 8; i++) {
        int u = i * 256 + t;
        int lr = u >> 3, cg = u & 7;
        *(bf16v8*)&obuf[(grow + lr) * 256 + 64 + cg * 8] = *(const bf16v8*)&Ot[lr * 72 + cg * 8];
    }
    {
        int c = t & 63, qtr = t >> 6;
        float s = 0.f, q = 0.f;
#pragma unroll
        for (int r = 0; r < 64; r++) {
            float v = __bfloat162float(Ot[(qtr * 64 + r) * 72 + c]);
            s += v; q += v * v;
        }
        sredS[t] = s; sredQ[t] = q;
        __syncthreads();
        if (t < 64) {
            float ss = sredS[t] + sredS[t + 64] + sredS[t + 128] + sredS[t + 192];
            float qq = sredQ[t] + sredQ[t + 64] + sredQ[t + 128] + sredQ[t + 192];
            atomicAdd(&stat[64 + t], ss);
            atomicAdd(&stat[256 + 64 + t], qq);
        }
    }
}

// ===== r15 mproj (both branches, 32 partials): grid (16, 4, 2) ===============
__global__ __launch_bounds__(256) void r15_mproj(
        const float* __restrict__ Wp2, const float* __restrict__ Wp3,
        const float* __restrict__ ctx_p, const float* __restrict__ lpart,
        bf16* __restrict__ M) {
    __shared__ float ctxS[16 * 68];
    __shared__ float ilS[16];
    int b = blockIdx.x, qq = blockIdx.y, z = blockIdx.z, t = threadIdx.x;
    int e = t & 63, cg = t >> 6;
    const float* Wp = z ? Wp3 : Wp2;
    long zb = (long)z * 16 + b;
#pragma unroll
    for (int i = 0; i < 4; i++) {
        int u = i * 256 + t;
        int c_l = u >> 6, d = u & 63;
        float s = 0.f;
#pragma unroll
        for (int p = 0; p < 32; p++)
            s += ctx_p[((zb * 32 + p) * 64 + qq * 16 + c_l) * 64 + d];
        ctxS[c_l * 68 + d] = s;
    }
    if (t < 16) {
        float l = 0.f;
#pragma unroll
        for (int p = 0; p < 32; p++)
            l += lpart[(zb * 32 + p) * 64 + qq * 16 + t];
        ilS[t] = 1.f / l;
    }
    float wreg[64];
#pragma unroll
    for (int i = 0; i < 16; i++) {
        float4 v = *(const float4*)&Wp[e * 64 + i * 4];
        wreg[i * 4 + 0] = v.x; wreg[i * 4 + 1] = v.y;
        wreg[i * 4 + 2] = v.z; wreg[i * 4 + 3] = v.w;
    }
    __syncthreads();
#pragma unroll
    for (int ci = 0; ci < 4; ci++) {
        int c_l = cg * 4 + ci;
        float a = 0.f;
#pragma unroll
        for (int dg = 0; dg < 16; dg++) {
            float4 cv = *(const float4*)&ctxS[c_l * 68 + dg * 4];
            a += wreg[dg * 4 + 0] * cv.x + wreg[dg * 4 + 1] * cv.y
               + wreg[dg * 4 + 2] * cv.z + wreg[dg * 4 + 3] * cv.w;
        }
        M[(long)z * 65536 + (long)b * 4096 + e * 64 + qq * 16 + c_l] =
            __float2bfloat16(a * ilS[c_l]);
    }
}

// --------- final: relu(bn2(y2) + bnsc(ysc)), write fp32 NCHW -----------------
__global__ void r6_final(const bf16* __restrict__ y2, const bf16* __restrict__ ysc,
                         const float* __restrict__ s2sums, const float* __restrict__ scsums,
                         const float* __restrict__ g2, const float* __restrict__ b2,
                         const float* __restrict__ gsc, const float* __restrict__ bsc,
                         float* __restrict__ out) {
    __shared__ float lo_[64 * 65];
    __shared__ float sc2[64], sh2[64], scc[64], shc[64];
    int b = blockIdx.z, c0 = blockIdx.y * 64, n0 = blockIdx.x * 64;
    int t = threadIdx.x;
    if (t < 64) {
        int ch = c0 + t;
        float m2 = s2sums[ch] * (1.f / 65536.f);
        float v2 = s2sums[256 + ch] * (1.f / 65536.f) - m2 * m2;
        float s = g2[ch] * rsqrtf(v2 + 1e-5f);
        sc2[t] = s; sh2[t] = b2[ch] - m2 * s;
        float mc = scsums[ch] * (1.f / 65536.f);
        float vc = scsums[256 + ch] * (1.f / 65536.f) - mc * mc;
        float s2_ = gsc[ch] * rsqrtf(vc + 1e-5f);
        scc[t] = s2_; shc[t] = bsc[ch] - mc * s2_;
    }
    __syncthreads();
    for (int half = 0; half < 2; half++) {
        int r = half * 32 + (t >> 3), cc = (t & 7) * 8;
        long row = (long)b * HW + n0 + r;
        bf16v8 a8 = *(const bf16v8*)&y2[row * 256 + c0 + cc];
        bf16v8 s8 = *(const bf16v8*)&ysc[row * 256 + c0 + cc];
#pragma unroll
        for (int j = 0; j < 8; j++) {
            int c = cc + j;
            float v = (float)a8[j] * sc2[c] + sh2[c] + (float)s8[j] * scc[c] + shc[c];
            lo_[c * 65 + r] = fmaxf(v, 0.f);
        }
    }
    __syncthreads();
#pragma unroll
    for (int i = 0; i < 4; i++) {
        int idx = i * 256 + t;
        int c = idx >> 4, r4 = (idx & 15) * 4;
        float4 w;
        w.x = lo_[c * 65 + r4 + 0];
        w.y = lo_[c * 65 + r4 + 1];
        w.z = lo_[c * 65 + r4 + 2];
        w.w = lo_[c * 65 + r4 + 3];
        *(float4*)&out[((long)(b * 256 + c0 + c)) * HW + n0 + r4] = w;
    }
}

extern "C" void kernel_launch(void* const* d_in, const int* in_sizes, int n_in,
                              void* d_out, int out_size, void* d_ws, size_t ws_size,
                              hipStream_t stream) {
    const float* x     = (const float*)d_in[0];
    const float* Wsc   = (const float*)d_in[1];
    const float* gsc   = (const float*)d_in[2];
    const float* bsc   = (const float*)d_in[3];
    const float* W1    = (const float*)d_in[4];
    const float* g1    = (const float*)d_in[5];
    const float* b1    = (const float*)d_in[6];
    const float* Wb0   = (const float*)d_in[7];
    const float* gb0   = (const float*)d_in[8];
    const float* bb0   = (const float*)d_in[9];
    const float* Wb1   = (const float*)d_in[10];
    const float* gb1   = (const float*)d_in[11];
    const float* bb1   = (const float*)d_in[12];
    const float* Wqkv2 = (const float*)d_in[13];
    const float* Wproj2= (const float*)d_in[14];
    const float* ga2   = (const float*)d_in[15];
    const float* ba2   = (const float*)d_in[16];
    const float* Wqkv3 = (const float*)d_in[17];
    const float* Wproj3= (const float*)d_in[18];
    const float* ga3   = (const float*)d_in[19];
    const float* ba3   = (const float*)d_in[20];
    const float* W2    = (const float*)d_in[21];
    const float* g2    = (const float*)d_in[22];
    const float* b2    = (const float*)d_in[23];

    // ---- workspace map ----
    char* ws = (char*)d_ws;
    float* stats = (float*)ws;                 // 2048 f
    bf16*  M     = (bf16*)(ws + 32768);        // 2 x 128 KiB -> ends 294912
    bf16*  wbase = (bf16*)(ws + 294912);       // 319488 B -> ends 614400
    bf16*  wsc_b = wbase;                      // [512][128] (Wsc|W1)
    bf16*  wb0_b = wbase + 65536;
    bf16*  wq2_b = wbase + 69632;
    bf16*  wq3_b = wbase + 81920;
    bf16*  w2_b  = wbase + 94208;
    bf16*  wb1p  = (bf16*)(ws + 614400);       // 73728 B -> ends 688128
    float* lpart = (float*)(ws + 688128);      // 256 KiB -> ends 950272 (< 1 MiB)
    bf16*  xT    = (bf16*)(ws + 1048576);      // 16 MiB; dead after big gemm
    float* ctx_p = (float*)(ws + 1048576);     // 16 MiB exactly (aliases dead xT)
    bf16*  ysc   = (bf16*)(ws + 17825792);     // 32 MiB, live to end
    bf16*  y1    = (bf16*)(ws + 51380224);     // 32 MiB; raw y1, dead after gkv/gq
    bf16*  y2    = y1;                         // conv2 output (y1 dead by then)
    bf16*  obuf  = (bf16*)d_out;               // 32 MiB bf16 scratch in d_out
    bf16*  qs    = (bf16*)((char*)d_out + 33554432); // 2 x 8 MiB [32,48)

    r4_cvt_w<<<dim3(768), 256, 0, stream>>>(Wsc, W1, Wb0, Wqkv2, Wqkv3, W2, Wb1,
                                            wbase, wb1p, stats);
    r4_cvt_x<<<dim3(64, 2, 16), 256, 0, stream>>>(x, xT);

    // conv_sc + conv1 fused (O=512), raw outputs + stats (ysc->set0, y1->set1)
    ga_gemm<128><<<dim3(32, 4, 16), 256, 0, stream>>>(
        xT, 128, wsc_b, 128,
        ysc, y1, 256, 256, stats, stats + 512, 0, 0,
        nullptr, nullptr, nullptr, nullptr, nullptr, nullptr, nullptr, nullptr, nullptr);

    // branch 1 (3x3): raw y1 staged, bn+relu in LDS
    r12_conv3<<<dim3(16, 16), 256, 0, stream>>>(y1, wb1p, obuf, stats + 1024,
                                                stats + 512, g1, b1);
    // fused k/v gemms + softmax-exp + ctx partials (no k/v in HBM)
    gkv_ctx<<<dim3(32, 2, 16), 256, 0, stream>>>(
        y1, wq2_b, wq3_b, ctx_p, lpart, stats + 512, g1, b1);
    // q (both branches) + branch0 1x1
    gq_gemm<<<dim3(32, 3, 16), 256, 0, stream>>>(
        y1, wq2_b, wq3_b, wb0_b, qs, obuf, stats + 1024,
        stats + 512, g1, b1);

    r15_mproj<<<dim3(16, 4, 2), 256, 0, stream>>>(Wproj2, Wproj3, ctx_p, lpart, M);
    gp_gemm<<<dim3(32, 2, 16), 256, 0, stream>>>(qs, M, obuf, stats + 1024);

    // conv2: stage raw obuf + quarter-concat bn+relu in LDS
    ga_gemm<256><<<dim3(32, 2, 16), 256, 0, stream>>>(
        obuf, 256, w2_b, 256,
        y2, y2, 1 << 28, 256, stats + 1536, stats + 1536, 0, 0,
        stats + 1024, gb0, bb0, gb1, bb1, ga2, ba2, ga3, ba3);

    r6_final<<<dim3(64, 4, 16), 256, 0, stream>>>(y2, ysc, stats + 1536, stats + 0,
                                                  g2, b2, gsc, bsc, (float*)d_out);
}

// Round 13
// 280.343 us; speedup vs baseline: 1.0384x; 1.0384x over previous
//
#include <hip/hip_runtime.h>
#include <hip/hip_bf16.h>

using bf16 = __hip_bfloat16;
typedef __bf16 bf16v8 __attribute__((ext_vector_type(8)));
typedef float f32x4 __attribute__((ext_vector_type(4)));

#define HW 4096      // 64*64 spatial per image
#define ROWS 65536   // 16*HW
#define BRSTRIDE 4194304   // 8 MiB bf16 elems per branch tensor (q/k/v)

#define AS1 const __attribute__((address_space(1))) void*
#define AS3 __attribute__((address_space(3))) void*

// ------- convert 6 weight matrices + pack Wb1 + zero stats (one launch) ------
__global__ void r4_cvt_w(const float* __restrict__ Wsc, const float* __restrict__ W1,
                         const float* __restrict__ Wb0,
                         const float* __restrict__ Wqkv2, const float* __restrict__ Wqkv3,
                         const float* __restrict__ W2, const float* __restrict__ Wb1,
                         bf16* __restrict__ wbase, bf16* __restrict__ wp,
                         float* __restrict__ stats) {
    int i = blockIdx.x * 256 + threadIdx.x;   // 768 blocks * 256 = 196608
    if (i < 2048) stats[i] = 0.f;
    if (i < 159744) {
        const float* s; int off;
        if      (i < 32768)  { s = Wsc;   off = i; }
        else if (i < 65536)  { s = W1;    off = i - 32768; }
        else if (i < 69632)  { s = Wb0;   off = i - 65536; }
        else if (i < 81920)  { s = Wqkv2; off = i - 69632; }
        else if (i < 94208)  { s = Wqkv3; off = i - 81920; }
        else                 { s = W2;    off = i - 94208; }
        wbase[i] = __float2bfloat16(s[off]);
    } else {
        int k = i - 159744;                  // 0..36863: Wb1 [o][c][3][3] -> [tap][o][c]
        int tap = k / 4096, rem = k % 4096;
        int o = rem >> 6, c = rem & 63;
        wp[k] = __float2bfloat16(Wb1[(size_t)(o * 64 + c) * 9 + tap]);
    }
}

// ------- convert+transpose x: fp32 [b][c=128][n] -> bf16 [b][n][c=128] -------
__global__ void r4_cvt_x(const float* __restrict__ x, bf16* __restrict__ xT) {
    __shared__ bf16 tile[64 * 65];
    int b = blockIdx.z, c0 = blockIdx.y * 64, n0 = blockIdx.x * 64;
    int t = threadIdx.x;
#pragma unroll
    for (int i = 0; i < 4; i++) {
        int idx = i * 256 + t;
        int cc = idx >> 4, n4 = (idx & 15) * 4;
        float4 v = *(const float4*)&x[((size_t)(b * 128 + c0 + cc)) * HW + n0 + n4];
        tile[(n4 + 0) * 65 + cc] = __float2bfloat16(v.x);
        tile[(n4 + 1) * 65 + cc] = __float2bfloat16(v.y);
        tile[(n4 + 2) * 65 + cc] = __float2bfloat16(v.z);
        tile[(n4 + 3) * 65 + cc] = __float2bfloat16(v.w);
    }
    __syncthreads();
#pragma unroll
    for (int i = 0; i < 2; i++) {
        int u = i * 256 + t;
        int nn = u >> 3, p = u & 7;
        bf16v8 v;
#pragma unroll
        for (int j = 0; j < 8; j++) v[j] = (__bf16)tile[nn * 65 + p * 8 + j];
        *(bf16v8*)&xT[((size_t)(b * HW + n0 + nn)) * 128 + c0 + p * 8] = v;
    }
}

// ===== ga_gemm: 128x128 tile, 4 waves (2x2), 64x64 per wave ==================
// K staged in 128-wide phases (1 drain/phase; LDS 64KB, 2 blocks/CU).
// Optional in-LDS bn+relu on A (tsums != nullptr); chunk p in 0..15,
// channel = k0 + ((p ^ (R&7)) << 3)  (swizzle involution).
template <int KK>
__global__ __launch_bounds__(256) void ga_gemm(
        const bf16* __restrict__ A, int a_stride,
        const bf16* __restrict__ W, int w_stride,
        bf16* __restrict__ out0, bf16* __restrict__ out1, int split,
        int out_stride,
        float* __restrict__ stat0, float* __restrict__ stat1,
        int scol0, int scol1,
        const float* __restrict__ tsums,
        const float* __restrict__ tg0, const float* __restrict__ tb0,
        const float* __restrict__ tg1, const float* __restrict__ tb1,
        const float* __restrict__ tg2, const float* __restrict__ tb2,
        const float* __restrict__ tg3, const float* __restrict__ tb3) {
    __shared__ bf16 shmem[2 * 128 * 128];     // As | Ws (64 KB); Ot aliases
    __shared__ float sredS[256], sredQ[256];
    __shared__ float scS[256], shS[256];
    bf16* As = shmem;                     // [128][128]
    bf16* Ws = shmem + 16384;             // [128][128]

    int t = threadIdx.x;
    int wave = t >> 6, lane = t & 63;
    int lo = lane & 15, quad = lane >> 4;
    int wr = wave >> 1, wc = wave & 1;
    int b = blockIdx.z;
    long grow = (long)b * HW + blockIdx.x * 128;
    int o0 = blockIdx.y * 128;
    const bf16* Wb = W + (long)o0 * w_stride;

    if (tsums) {   // quarter-concat bn params for the 256 input channels
        int qi = t >> 6, ci = t & 63;
        const float* gp = qi == 0 ? tg0 : qi == 1 ? tg1 : qi == 2 ? tg2 : tg3;
        const float* bp = qi == 0 ? tb0 : qi == 1 ? tb1 : qi == 2 ? tb2 : tb3;
        float mean = tsums[t] * (1.f / 65536.f);
        float var  = tsums[256 + t] * (1.f / 65536.f) - mean * mean;
        float s = gp[ci] * rsqrtf(var + 1e-5f);
        scS[t] = s; shS[t] = bp[ci] - mean * s;
    }

    f32x4 acc[4][4];
#pragma unroll
    for (int m = 0; m < 4; m++)
#pragma unroll
        for (int n = 0; n < 4; n++) acc[m][n] = (f32x4){0.f, 0.f, 0.f, 0.f};

#pragma unroll
    for (int ph = 0; ph < KK / 128; ph++) {
        int k0 = ph * 128;
        // stage A+W 128x128 halves: 2048 16B-chunks each, 8 instrs/wave/tensor
#pragma unroll
        for (int j = 0; j < 8; j++) {
            int i = j * 4 + wave;          // 0..31
            int ci = i * 64 + lane;        // 0..2047
            int R = ci >> 4, cc = ci & 15;
            int sw = ((cc ^ (R & 7)) << 3);
            __builtin_amdgcn_global_load_lds(
                (AS1)(A + (grow + R) * (long)a_stride + k0 + sw),
                (AS3)(As + i * 512), 16, 0, 0);
            __builtin_amdgcn_global_load_lds(
                (AS1)(Wb + (long)R * w_stride + k0 + sw),
                (AS3)(Ws + i * 512), 16, 0, 0);
        }
        asm volatile("s_waitcnt vmcnt(0)" ::: "memory");
        __syncthreads();
        if (tsums) {   // bn+relu the staged A tile in LDS
#pragma unroll
            for (int i = 0; i < 8; i++) {
                int ci = i * 256 + t;      // 0..2047
                int R = ci >> 4, p = ci & 15;
                int chb = k0 + ((p ^ (R & 7)) << 3);
                bf16v8 v = *(const bf16v8*)&As[R * 128 + p * 8];
#pragma unroll
                for (int j = 0; j < 8; j++) {
                    float f = (float)v[j] * scS[chb + j] + shS[chb + j];
                    v[j] = (__bf16)fmaxf(f, 0.f);
                }
                *(bf16v8*)&As[R * 128 + p * 8] = v;
            }
            __syncthreads();
        }
#pragma unroll
        for (int ks = 0; ks < 128; ks += 32) {
            int kk = (ks >> 3) + quad;     // 0..15
            bf16v8 av[4], wv[4];
#pragma unroll
            for (int m = 0; m < 4; m++) {
                int R = wr * 64 + m * 16 + lo;
                av[m] = *(const bf16v8*)&As[R * 128 + ((kk ^ (R & 7)) << 3)];
            }
#pragma unroll
            for (int n = 0; n < 4; n++) {
                int R = wc * 64 + n * 16 + lo;
                wv[n] = *(const bf16v8*)&Ws[R * 128 + ((kk ^ (R & 7)) << 3)];
            }
#pragma unroll
            for (int m = 0; m < 4; m++)
#pragma unroll
                for (int n = 0; n < 4; n++)
                    acc[m][n] = __builtin_amdgcn_mfma_f32_16x16x32_bf16(av[m], wv[n], acc[m][n], 0, 0, 0);
        }
        __syncthreads();
    }

    bf16* Ot = shmem;                      // [128][136] = 34816 B, aliases As/Ws
#pragma unroll
    for (int m = 0; m < 4; m++)
#pragma unroll
        for (int n = 0; n < 4; n++)
#pragma unroll
            for (int r = 0; r < 4; r++)
                Ot[(wr * 64 + m * 16 + quad * 4 + r) * 136 + wc * 64 + n * 16 + lo] =
                    __float2bfloat16(acc[m][n][r]);
    __syncthreads();
    bool low = o0 < split;
    bf16* op = low ? out0 : out1;
    int oc0 = low ? o0 : o0 - split;
#pragma unroll
    for (int i = 0; i < 8; i++) {
        int u = i * 256 + t;
        int lr = u >> 4, cg = u & 15;
        *(bf16v8*)&op[(grow + lr) * (long)out_stride + oc0 + cg * 8] =
            *(const bf16v8*)&Ot[lr * 136 + cg * 8];
    }
    if (stat0) {
        int c = t & 127, half = t >> 7;
        float s = 0.f, q = 0.f;
#pragma unroll
        for (int r = 0; r < 64; r++) {
            float v = __bfloat162float(Ot[(half * 64 + r) * 136 + c]);
            s += v; q += v * v;
        }
        sredS[t] = s; sredQ[t] = q;
        __syncthreads();
        if (t < 128) {
            float ss = sredS[t] + sredS[t + 128];
            float qq = sredQ[t] + sredQ[t + 128];
            float* st = low ? stat0 : stat1;
            int ci = (low ? scol0 + o0 : scol1 + o0 - split) + c;
            atomicAdd(&st[ci], ss);
            atomicAdd(&st[256 + ci], qq);
        }
    }
}

// ===== gq_gemm: 256x64 tile, K=64. Combined qkv (both branches) + branch0 ====
// grid (16, 7, 16). A = raw y1 slice; bn+relu applied in LDS after staging.
__global__ __launch_bounds__(256) void gq_gemm(
        const bf16* __restrict__ y1,
        const bf16* __restrict__ wq2, const bf16* __restrict__ wq3,
        const bf16* __restrict__ wb0,
        bf16* __restrict__ qs, bf16* __restrict__ ks, bf16* __restrict__ vs,
        bf16* __restrict__ obuf, float* __restrict__ stats,
        const float* __restrict__ asums,
        const float* __restrict__ g1, const float* __restrict__ b1) {
    __shared__ bf16 shmem[256 * 64 + 64 * 64];
    __shared__ float sredS[256], sredQ[256];
    __shared__ float scS[64], shS[64];
    bf16* As = shmem;
    bf16* Ws = shmem + 256 * 64;

    int t = threadIdx.x;
    int wave = t >> 6, lane = t & 63;
    int lo = lane & 15, quad = lane >> 4;
    int b = blockIdx.z, y = blockIdx.y;
    long grow = (long)b * HW + blockIdx.x * 256;

    const bf16* Ab; const bf16* Wb; bf16* outp; int ostride; float* st; int col0;
    if (y == 6) {
        Ab = y1; Wb = wb0; outp = obuf; ostride = 256; st = stats; col0 = 0;
    } else {
        int br = y / 3, sel = y - br * 3;
        col0 = 128 + br * 64;
        Ab = y1 + col0;
        Wb = (br ? wq3 : wq2) + sel * 4096;
        outp = (sel == 0 ? qs : sel == 1 ? ks : vs) + (long)br * BRSTRIDE;
        ostride = 64; st = nullptr;
    }
    if (t < 64) {
        int ch = col0 + t;
        float mean = asums[ch] * (1.f / 65536.f);
        float var  = asums[256 + ch] * (1.f / 65536.f) - mean * mean;
        float s = g1[ch] * rsqrtf(var + 1e-5f);
        scS[t] = s; shS[t] = b1[ch] - mean * s;
    }

    f32x4 acc[4][4];
#pragma unroll
    for (int m = 0; m < 4; m++)
#pragma unroll
        for (int n = 0; n < 4; n++) acc[m][n] = (f32x4){0.f, 0.f, 0.f, 0.f};

#pragma unroll
    for (int j = 0; j < 8; j++) {          // A: 256 rows x 8 chunks = 2048
        int ci = (j * 4 + wave) * 64 + lane;
        int R = ci >> 3, cc = ci & 7;
        __builtin_amdgcn_global_load_lds(
            (AS1)(Ab + (grow + R) * 256L + ((cc ^ (R & 7)) << 3)),
            (AS3)(As + (j * 4 + wave) * 512), 16, 0, 0);
    }
#pragma unroll
    for (int j = 0; j < 2; j++) {          // W: 64 rows x 8 chunks = 512
        int ci = (j * 4 + wave) * 64 + lane;
        int R = ci >> 3, cc = ci & 7;
        __builtin_amdgcn_global_load_lds(
            (AS1)(Wb + R * 64 + ((cc ^ (R & 7)) << 3)),
            (AS3)(Ws + (j * 4 + wave) * 512), 16, 0, 0);
    }
    asm volatile("s_waitcnt vmcnt(0)" ::: "memory");
    __syncthreads();
    // bn+relu the staged A tile in LDS (raw y1 -> h)
#pragma unroll
    for (int i = 0; i < 8; i++) {
        int ci = i * 256 + t;
        int R = ci >> 3, p = ci & 7;
        int chb = (p ^ (R & 7)) << 3;
        bf16v8 v = *(const bf16v8*)&As[R * 64 + p * 8];
#pragma unroll
        for (int j = 0; j < 8; j++) {
            float f = (float)v[j] * scS[chb + j] + shS[chb + j];
            v[j] = (__bf16)fmaxf(f, 0.f);
        }
        *(bf16v8*)&As[R * 64 + p * 8] = v;
    }
    __syncthreads();

#pragma unroll
    for (int ks_ = 0; ks_ < 64; ks_ += 32) {
        bf16v8 av[4], wv[4];
#pragma unroll
        for (int m = 0; m < 4; m++) {
            int R = wave * 64 + m * 16 + lo;
            av[m] = *(const bf16v8*)&As[R * 64 + ((((ks_ >> 3) + quad) ^ (R & 7)) << 3)];
        }
#pragma unroll
        for (int n = 0; n < 4; n++) {
            int o = n * 16 + lo;
            wv[n] = *(const bf16v8*)&Ws[o * 64 + ((((ks_ >> 3) + quad) ^ (o & 7)) << 3)];
        }
#pragma unroll
        for (int m = 0; m < 4; m++)
#pragma unroll
            for (int n = 0; n < 4; n++)
                acc[m][n] = __builtin_amdgcn_mfma_f32_16x16x32_bf16(av[m], wv[n], acc[m][n], 0, 0, 0);
    }
    __syncthreads();

    bf16* Ot = shmem;                       // [256][72]
#pragma unroll
    for (int m = 0; m < 4; m++)
#pragma unroll
        for (int n = 0; n < 4; n++)
#pragma unroll
            for (int r = 0; r < 4; r++)
                Ot[(wave * 64 + m * 16 + quad * 4 + r) * 72 + n * 16 + lo] =
                    __float2bfloat16(acc[m][n][r]);
    __syncthreads();
#pragma unroll
    for (int i = 0; i < 8; i++) {
        int u = i * 256 + t;
        int lr = u >> 3, cg = u & 7;
        *(bf16v8*)&outp[(grow + lr) * (long)ostride + cg * 8] =
            *(const bf16v8*)&Ot[lr * 72 + cg * 8];
    }
    if (st) {
        int c = t & 63, qtr = t >> 6;
        float s = 0.f, q = 0.f;
#pragma unroll
        for (int r = 0; r < 64; r++) {
            float v = __bfloat162float(Ot[(qtr * 64 + r) * 72 + c]);
            s += v; q += v * v;
        }
        sredS[t] = s; sredQ[t] = q;
        __syncthreads();
        if (t < 64) {
            float ss = sredS[t] + sredS[t + 64] + sredS[t + 128] + sredS[t + 192];
            float qq = sredQ[t] + sredQ[t + 64] + sredQ[t + 128] + sredQ[t + 192];
            atomicAdd(&st[t], ss);
            atomicAdd(&st[256 + t], qq);
        }
    }
}

// ===== gp_gemm: PV for both branches. grid (16, 2, 16), y = branch ===========
__global__ __launch_bounds__(256) void gp_gemm(
        const bf16* __restrict__ qs, const bf16* __restrict__ M,
        bf16* __restrict__ obuf, float* __restrict__ stats) {
    __shared__ bf16 shmem[256 * 64 + 64 * 64];
    __shared__ float sredS[256], sredQ[256];
    bf16* As = shmem;
    bf16* Ws = shmem + 256 * 64;

    int t = threadIdx.x;
    int wave = t >> 6, lane = t & 63;
    int lo = lane & 15, quad = lane >> 4;
    int b = blockIdx.z, y = blockIdx.y;
    long grow = (long)b * HW + blockIdx.x * 256;
    const bf16* Ab = qs + (long)y * BRSTRIDE;
    const bf16* Wb = M + y * 65536 + (long)b * 4096;
    int oc0 = 128 + y * 64;

    f32x4 acc[4][4];
#pragma unroll
    for (int m = 0; m < 4; m++)
#pragma unroll
        for (int n = 0; n < 4; n++) acc[m][n] = (f32x4){0.f, 0.f, 0.f, 0.f};

#pragma unroll
    for (int j = 0; j < 8; j++) {          // A: 256 rows x 8 chunks (stride 64)
        int ci = (j * 4 + wave) * 64 + lane;
        int R = ci >> 3, cc = ci & 7;
        __builtin_amdgcn_global_load_lds(
            (AS1)(Ab + (grow + R) * 64L + ((cc ^ (R & 7)) << 3)),
            (AS3)(As + (j * 4 + wave) * 512), 16, 0, 0);
    }
#pragma unroll
    for (int j = 0; j < 2; j++) {          // W: 64 rows x 8 chunks
        int ci = (j * 4 + wave) * 64 + lane;
        int R = ci >> 3, cc = ci & 7;
        __builtin_amdgcn_global_load_lds(
            (AS1)(Wb + R * 64 + ((cc ^ (R & 7)) << 3)),
            (AS3)(Ws + (j * 4 + wave) * 512), 16, 0, 0);
    }
    asm volatile("s_waitcnt vmcnt(0)" ::: "memory");
    __syncthreads();

#pragma unroll
    for (int ks_ = 0; ks_ < 64; ks_ += 32) {
        bf16v8 av[4], wv[4];
#pragma unroll
        for (int m = 0; m < 4; m++) {
            int R = wave * 64 + m * 16 + lo;
            av[m] = *(const bf16v8*)&As[R * 64 + ((((ks_ >> 3) + quad) ^ (R & 7)) << 3)];
        }
#pragma unroll
        for (int n = 0; n < 4; n++) {
            int o = n * 16 + lo;
            wv[n] = *(const bf16v8*)&Ws[o * 64 + ((((ks_ >> 3) + quad) ^ (o & 7)) << 3)];
        }
#pragma unroll
        for (int m = 0; m < 4; m++)
#pragma unroll
            for (int n = 0; n < 4; n++)
                acc[m][n] = __builtin_amdgcn_mfma_f32_16x16x32_bf16(av[m], wv[n], acc[m][n], 0, 0, 0);
    }
    __syncthreads();

    bf16* Ot = shmem;                       // [256][72]
#pragma unroll
    for (int m = 0; m < 4; m++)
#pragma unroll
        for (int n = 0; n < 4; n++)
#pragma unroll
            for (int r = 0; r < 4; r++)
                Ot[(wave * 64 + m * 16 + quad * 4 + r) * 72 + n * 16 + lo] =
                    __float2bfloat16(acc[m][n][r]);
    __syncthreads();
#pragma unroll
    for (int i = 0; i < 8; i++) {
        int u = i * 256 + t;
        int lr = u >> 3, cg = u & 7;
        *(bf16v8*)&obuf[(grow + lr) * 256L + oc0 + cg * 8] =
            *(const bf16v8*)&Ot[lr * 72 + cg * 8];
    }
    {
        int c = t & 63, qtr = t >> 6;
        float s = 0.f, q = 0.f;
#pragma unroll
        for (int r = 0; r < 64; r++) {
            float v = __bfloat162float(Ot[(qtr * 64 + r) * 72 + c]);
            s += v; q += v * v;
        }
        sredS[t] = s; sredQ[t] = q;
        __syncthreads();
        if (t < 64) {
            float ss = sredS[t] + sredS[t + 64] + sredS[t + 128] + sredS[t + 192];
            float qq = sredQ[t] + sredQ[t + 64] + sredQ[t + 128] + sredQ[t + 192];
            atomicAdd(&stats[oc0 + t], ss);
            atomicAdd(&stats[256 + oc0 + t], qq);
        }
    }
}

// ===== r12 conv3: 4 y-rows/block; raw y1 staged, bn+relu in LDS ==============
__global__ __launch_bounds__(256) void r12_conv3(
        const bf16* __restrict__ hT, const bf16* __restrict__ wp,
        bf16* __restrict__ obuf, float* __restrict__ stat,
        const float* __restrict__ asums,
        const float* __restrict__ g1, const float* __restrict__ b1) {
    __shared__ bf16 As[6 * 66 * 64];
    __shared__ bf16 Wt[9 * 64 * 64];
    __shared__ float sredS[256], sredQ[256];
    __shared__ float scS[64], shS[64];

    int t = threadIdx.x;
    int wave = t >> 6, lane = t & 63;
    int lo = lane & 15, quad = lane >> 4;
    int b = blockIdx.y, y0 = blockIdx.x * 4;

    if (t < 64) {   // channels 64..127 of y1
        int ch = 64 + t;
        float mean = asums[ch] * (1.f / 65536.f);
        float var  = asums[256 + ch] * (1.f / 65536.f) - mean * mean;
        float s = g1[ch] * rsqrtf(var + 1e-5f);
        scS[t] = s; shS[t] = b1[ch] - mean * s;
    }

#pragma unroll
    for (int j = 0; j < 18; j++) {
        int i = j * 4 + wave;
        int ci = i * 64 + lane;
        int tap = ci >> 9, rem = ci & 511, o = rem >> 3, ck = rem & 7;
        __builtin_amdgcn_global_load_lds(
            (AS1)(wp + tap * 4096 + o * 64 + ((ck ^ (o & 7)) << 3)),
            (AS3)(Wt + i * 512), 16, 0, 0);
    }
#pragma unroll
    for (int j = 0; j < 12; j++) {
        int i = j * 4 + wave;            // 0..47
        int row = i >> 3, seg = i & 7;
        int yy = y0 - 1 + row;
        if (yy >= 0 && yy < 64) {
            int xg = seg * 8 + (lane >> 3), ck = lane & 7;
            __builtin_amdgcn_global_load_lds(
                (AS1)(hT + ((long)b * HW + yy * 64 + xg) * 256 + 64 + ((ck ^ (xg & 7)) << 3)),
                (AS3)(As + row * 4224 + 64 + seg * 512), 16, 0, 0);
        } else {
            *(bf16v8*)&As[row * 4224 + 64 + seg * 512 + lane * 8] = (bf16v8){0,0,0,0,0,0,0,0};
        }
    }
    if (t < 96) {
        int yr = t >> 4, side = (t >> 3) & 1, ck = t & 7;
        *(bf16v8*)&As[yr * 4224 + (side ? 65 : 0) * 64 + ck * 8] = (bf16v8){0,0,0,0,0,0,0,0};
    }
    asm volatile("s_waitcnt vmcnt(0)" ::: "memory");
    __syncthreads();
    // bn+relu valid region only (padding stays zero = pad-after-activation)
#pragma unroll
    for (int i = 0; i < 12; i++) {
        int ci = i * 256 + t;            // 3072 chunks: [row 6][x 64][p 8]
        int row = ci >> 9, rem = ci & 511;
        int xg = rem >> 3, p = rem & 7;
        int yy = y0 - 1 + row;
        if (yy >= 0 && yy < 64) {
            int chb = (p ^ (xg & 7)) << 3;
            bf16v8 v = *(const bf16v8*)&As[row * 4224 + (xg + 1) * 64 + p * 8];
#pragma unroll
            for (int j = 0; j < 8; j++) {
                float f = (float)v[j] * scS[chb + j] + shS[chb + j];
                v[j] = (__bf16)fmaxf(f, 0.f);
            }
            *(bf16v8*)&As[row * 4224 + (xg + 1) * 64 + p * 8] = v;
        }
    }
    __syncthreads();

    f32x4 acc[4][4];   // [m spatial 16][ot out 16]
#pragma unroll
    for (int m = 0; m < 4; m++)
#pragma unroll
        for (int n = 0; n < 4; n++) acc[m][n] = (f32x4){0.f, 0.f, 0.f, 0.f};

#pragma unroll
    for (int tap = 0; tap < 9; tap++) {
        int dy = tap / 3 - 1, dx = tap % 3 - 1;
        int yr = wave + 1 + dy;
#pragma unroll
        for (int ks8 = 0; ks8 < 8; ks8 += 4) {
            int kk = ks8 + quad;
            bf16v8 wv[4];
#pragma unroll
            for (int ot = 0; ot < 4; ot++) {
                int o = ot * 16 + lo;
                wv[ot] = *(const bf16v8*)&Wt[tap * 4096 + o * 64 + ((kk ^ (o & 7)) << 3)];
            }
#pragma unroll
            for (int m = 0; m < 4; m++) {
                int xp = m * 16 + lo + dx;
                bf16v8 av = *(const bf16v8*)&As[yr * 4224 + (xp + 1) * 64 + ((kk ^ (xp & 7)) << 3)];
#pragma unroll
                for (int ot = 0; ot < 4; ot++)
                    acc[m][ot] = __builtin_amdgcn_mfma_f32_16x16x32_bf16(av, wv[ot], acc[m][ot], 0, 0, 0);
            }
        }
    }
    __syncthreads();

    bf16* Ot = As;                        // [256][72]
#pragma unroll
    for (int m = 0; m < 4; m++)
#pragma unroll
        for (int ot = 0; ot < 4; ot++)
#pragma unroll
            for (int r = 0; r < 4; r++)
                Ot[(wave * 64 + m * 16 + quad * 4 + r) * 72 + ot * 16 + lo] =
                    __float2bfloat16(acc[m][ot][r]);
    __syncthreads();

    long grow = (long)b * HW + y0 * 64;
#pragma unroll
    for (int i = 0; i < 8; i++) {
        int u = i * 256 + t;
        int lr = u >> 3, cg = u & 7;
        *(bf16v8*)&obuf[(grow + lr) * 256 + 64 + cg * 8] = *(const bf16v8*)&Ot[lr * 72 + cg * 8];
    }
    {
        int c = t & 63, qtr = t >> 6;
        float s = 0.f, q = 0.f;
#pragma unroll
        for (int r = 0; r < 64; r++) {
            float v = __bfloat162float(Ot[(qtr * 64 + r) * 72 + c]);
            s += v; q += v * v;
        }
        sredS[t] = s; sredQ[t] = q;
        __syncthreads();
        if (t < 64) {
            float ss = sredS[t] + sredS[t + 64] + sredS[t + 128] + sredS[t + 192];
            float qq = sredQ[t] + sredQ[t + 64] + sredQ[t + 128] + sredQ[t + 192];
            atomicAdd(&stat[64 + t], ss);
            atomicAdd(&stat[256 + 64 + t], qq);
        }
    }
}

// ===== r14 softctx (max-free, both branches): grid (16, 16, 2) ===============
__global__ __launch_bounds__(256) void r14_softctx(
        const bf16* __restrict__ ks_t, const bf16* __restrict__ vs_t,
        float* __restrict__ ctx_p, float* __restrict__ lpart) {
    __shared__ bf16 Ks[64 * 136];
    __shared__ bf16 Vs[64 * 136];
    __shared__ float red[32 * 64];
    int t = threadIdx.x;
    int wave = t >> 6, lane = t & 63;
    int lo = lane & 15, quad = lane >> 4;
    int b = blockIdx.y, bx = blockIdx.x, z = blockIdx.z;
    const bf16* kb = ks_t + (long)z * BRSTRIDE;
    const bf16* vb = vs_t + (long)z * BRSTRIDE;

    f32x4 acc[4];
#pragma unroll
    for (int ot = 0; ot < 4; ot++) acc[ot] = (f32x4){0.f, 0.f, 0.f, 0.f};
    float sm[8];
#pragma unroll
    for (int j = 0; j < 8; j++) sm[j] = 0.f;

    for (int it = 0; it < 2; it++) {
        long n0 = ((long)bx * 2 + it) * 128;
        __syncthreads();
#pragma unroll
        for (int sub = 0; sub < 4; sub++) {
            int r = sub * 32 + (t >> 3), cg = t & 7;
            long row = (long)b * HW + n0 + r;
            bf16v8 k8 = *(const bf16v8*)(kb + row * 64 + cg * 8);
            bf16v8 v8 = *(const bf16v8*)(vb + row * 64 + cg * 8);
#pragma unroll
            for (int j = 0; j < 8; j++) {
                int c = cg * 8 + j;
                float e = expf((float)k8[j]);
                sm[j] += e;
                Ks[c * 136 + r] = __float2bfloat16(e);
                Vs[c * 136 + r] = (bf16)v8[j];
            }
        }
        __syncthreads();
#pragma unroll
        for (int ks = 0; ks < 128; ks += 32) {
            bf16v8 av = *(const bf16v8*)&Ks[(wave * 16 + lo) * 136 + ks + quad * 8];
#pragma unroll
            for (int ot = 0; ot < 4; ot++) {
                bf16v8 bv = *(const bf16v8*)&Vs[(ot * 16 + lo) * 136 + ks + quad * 8];
                acc[ot] = __builtin_amdgcn_mfma_f32_16x16x32_bf16(av, bv, acc[ot], 0, 0, 0);
            }
        }
    }
    long blk = ((long)z * 16 + b) * 16 + bx;
#pragma unroll
    for (int ot = 0; ot < 4; ot++) {
#pragma unroll
        for (int r = 0; r < 4; r++) {
            int c = wave * 16 + quad * 4 + r;
            int d = ot * 16 + lo;
            ctx_p[(blk * 64 + c) * 64 + d] = acc[ot][r];
        }
    }
    {
        int rg = t >> 3, cg = t & 7;
#pragma unroll
        for (int j = 0; j < 8; j++) red[rg * 64 + cg * 8 + j] = sm[j];
        __syncthreads();
        if (t < 64) {
            float s = 0.f;
#pragma unroll
            for (int i = 0; i < 32; i++) s += red[i * 64 + t];
            lpart[blk * 64 + t] = s;
        }
    }
}

// ===== r15 mproj (both branches): grid (16, 4, 2) ============================
__global__ __launch_bounds__(256) void r15_mproj(
        const float* __restrict__ Wp2, const float* __restrict__ Wp3,
        const float* __restrict__ ctx_p, const float* __restrict__ lpart,
        bf16* __restrict__ M) {
    __shared__ float ctxS[16 * 68];
    __shared__ float ilS[16];
    int b = blockIdx.x, qq = blockIdx.y, z = blockIdx.z, t = threadIdx.x;
    int e = t & 63, cg = t >> 6;
    const float* Wp = z ? Wp3 : Wp2;
    long zb = (long)z * 16 + b;
#pragma unroll
    for (int i = 0; i < 4; i++) {
        int u = i * 256 + t;
        int c_l = u >> 6, d = u & 63;
        float s = 0.f;
#pragma unroll
        for (int p = 0; p < 16; p++)
            s += ctx_p[((zb * 16 + p) * 64 + qq * 16 + c_l) * 64 + d];
        ctxS[c_l * 68 + d] = s;
    }
    if (t < 16) {
        float l = 0.f;
#pragma unroll
        for (int p = 0; p < 16; p++)
            l += lpart[(zb * 16 + p) * 64 + qq * 16 + t];
        ilS[t] = 1.f / l;
    }
    float wreg[64];
#pragma unroll
    for (int i = 0; i < 16; i++) {
        float4 v = *(const float4*)&Wp[e * 64 + i * 4];
        wreg[i * 4 + 0] = v.x; wreg[i * 4 + 1] = v.y;
        wreg[i * 4 + 2] = v.z; wreg[i * 4 + 3] = v.w;
    }
    __syncthreads();
#pragma unroll
    for (int ci = 0; ci < 4; ci++) {
        int c_l = cg * 4 + ci;
        float a = 0.f;
#pragma unroll
        for (int dg = 0; dg < 16; dg++) {
            float4 cv = *(const float4*)&ctxS[c_l * 68 + dg * 4];
            a += wreg[dg * 4 + 0] * cv.x + wreg[dg * 4 + 1] * cv.y
               + wreg[dg * 4 + 2] * cv.z + wreg[dg * 4 + 3] * cv.w;
        }
        M[(long)z * 65536 + (long)b * 4096 + e * 64 + qq * 16 + c_l] =
            __float2bfloat16(a * ilS[c_l]);
    }
}

// --------- final: relu(bn2(y2) + bnsc(ysc)), write fp32 NCHW -----------------
__global__ void r6_final(const bf16* __restrict__ y2, const bf16* __restrict__ ysc,
                         const float* __restrict__ s2sums, const float* __restrict__ scsums,
                         const float* __restrict__ g2, const float* __restrict__ b2,
                         const float* __restrict__ gsc, const float* __restrict__ bsc,
                         float* __restrict__ out) {
    __shared__ float lo_[64 * 65];
    __shared__ float sc2[64], sh2[64], scc[64], shc[64];
    int b = blockIdx.z, c0 = blockIdx.y * 64, n0 = blockIdx.x * 64;
    int t = threadIdx.x;
    if (t < 64) {
        int ch = c0 + t;
        float m2 = s2sums[ch] * (1.f / 65536.f);
        float v2 = s2sums[256 + ch] * (1.f / 65536.f) - m2 * m2;
        float s = g2[ch] * rsqrtf(v2 + 1e-5f);
        sc2[t] = s; sh2[t] = b2[ch] - m2 * s;
        float mc = scsums[ch] * (1.f / 65536.f);
        float vc = scsums[256 + ch] * (1.f / 65536.f) - mc * mc;
        float s2_ = gsc[ch] * rsqrtf(vc + 1e-5f);
        scc[t] = s2_; shc[t] = bsc[ch] - mc * s2_;
    }
    __syncthreads();
    for (int half = 0; half < 2; half++) {
        int r = half * 32 + (t >> 3), cc = (t & 7) * 8;
        long row = (long)b * HW + n0 + r;
        bf16v8 a8 = *(const bf16v8*)&y2[row * 256 + c0 + cc];
        bf16v8 s8 = *(const bf16v8*)&ysc[row * 256 + c0 + cc];
#pragma unroll
        for (int j = 0; j < 8; j++) {
            int c = cc + j;
            float v = (float)a8[j] * sc2[c] + sh2[c] + (float)s8[j] * scc[c] + shc[c];
            lo_[c * 65 + r] = fmaxf(v, 0.f);
        }
    }
    __syncthreads();
#pragma unroll
    for (int i = 0; i < 4; i++) {
        int idx = i * 256 + t;
        int c = idx >> 4, r4 = (idx & 15) * 4;
        float4 w;
        w.x = lo_[c * 65 + r4 + 0];
        w.y = lo_[c * 65 + r4 + 1];
        w.z = lo_[c * 65 + r4 + 2];
        w.w = lo_[c * 65 + r4 + 3];
        *(float4*)&out[((long)(b * 256 + c0 + c)) * HW + n0 + r4] = w;
    }
}

extern "C" void kernel_launch(void* const* d_in, const int* in_sizes, int n_in,
                              void* d_out, int out_size, void* d_ws, size_t ws_size,
                              hipStream_t stream) {
    const float* x     = (const float*)d_in[0];
    const float* Wsc   = (const float*)d_in[1];
    const float* gsc   = (const float*)d_in[2];
    const float* bsc   = (const float*)d_in[3];
    const float* W1    = (const float*)d_in[4];
    const float* g1    = (const float*)d_in[5];
    const float* b1    = (const float*)d_in[6];
    const float* Wb0   = (const float*)d_in[7];
    const float* gb0   = (const float*)d_in[8];
    const float* bb0   = (const float*)d_in[9];
    const float* Wb1   = (const float*)d_in[10];
    const float* gb1   = (const float*)d_in[11];
    const float* bb1   = (const float*)d_in[12];
    const float* Wqkv2 = (const float*)d_in[13];
    const float* Wproj2= (const float*)d_in[14];
    const float* ga2   = (const float*)d_in[15];
    const float* ba2   = (const float*)d_in[16];
    const float* Wqkv3 = (const float*)d_in[17];
    const float* Wproj3= (const float*)d_in[18];
    const float* ga3   = (const float*)d_in[19];
    const float* ba3   = (const float*)d_in[20];
    const float* W2    = (const float*)d_in[21];
    const float* g2    = (const float*)d_in[22];
    const float* b2    = (const float*)d_in[23];

    // ---- workspace map ----
    char* ws = (char*)d_ws;
    float* stats = (float*)ws;                 // 2048 f
    bf16*  M     = (bf16*)(ws + 32768);        // 2 x 128 KiB -> ends 294912
    bf16*  wbase = (bf16*)(ws + 294912);       // 319488 B -> ends 614400
    bf16*  wsc_b = wbase;                      // [512][128] (Wsc|W1)
    bf16*  wb0_b = wbase + 65536;
    bf16*  wq2_b = wbase + 69632;
    bf16*  wq3_b = wbase + 81920;
    bf16*  w2_b  = wbase + 94208;
    bf16*  wb1p  = (bf16*)(ws + 614400);       // 73728 B -> ends 688128
    bf16*  xT    = (bf16*)(ws + 1048576);      // 16 MiB; dead after big gemm
    bf16*  vs    = (bf16*)(ws + 1048576);      // 2 x 8 MiB, aliases dead xT
    bf16*  ysc   = (bf16*)(ws + 17825792);     // 32 MiB, live to end
    bf16*  y1    = (bf16*)(ws + 51380224);     // 32 MiB; dead after gq_gemm
    float* ctx_p = (float*)(ws + 51380224);    // 8 MiB (aliases dead y1)
    float* lpart = (float*)(ws + 51380224 + 8388608); // 128 KiB
    bf16*  y2    = y1;                         // conv2 writes after ctx_p dead
    bf16*  obuf  = (bf16*)d_out;               // 32 MiB bf16 scratch in d_out
    bf16*  qs    = (bf16*)((char*)d_out + 33554432); // 2 x 8 MiB [32,48)
    bf16*  ks    = (bf16*)((char*)d_out + 50331648); // 2 x 8 MiB [48,64)

    r4_cvt_w<<<dim3(768), 256, 0, stream>>>(Wsc, W1, Wb0, Wqkv2, Wqkv3, W2, Wb1,
                                            wbase, wb1p, stats);
    r4_cvt_x<<<dim3(64, 2, 16), 256, 0, stream>>>(x, xT);

    // conv_sc + conv1 fused (O=512), raw outputs + stats (ysc->set0, y1->set1)
    ga_gemm<128><<<dim3(32, 4, 16), 256, 0, stream>>>(
        xT, 128, wsc_b, 128,
        ysc, y1, 256, 256, stats, stats + 512, 0, 0,
        nullptr, nullptr, nullptr, nullptr, nullptr, nullptr, nullptr, nullptr, nullptr);

    // branch 1 (3x3) and combined {branch0 1x1 + qkv both LGA branches};
    // both stage raw y1 and apply bn+relu in LDS
    r12_conv3<<<dim3(16, 16), 256, 0, stream>>>(y1, wb1p, obuf, stats + 1024,
                                                stats + 512, g1, b1);
    gq_gemm<<<dim3(16, 7, 16), 256, 0, stream>>>(
        y1, wq2_b, wq3_b, wb0_b, qs, ks, vs, obuf, stats + 1024,
        stats + 512, g1, b1);

    // LGA pipeline, both branches per launch
    r14_softctx<<<dim3(16, 16, 2), 256, 0, stream>>>(ks, vs, ctx_p, lpart);
    r15_mproj<<<dim3(16, 4, 2), 256, 0, stream>>>(Wproj2, Wproj3, ctx_p, lpart, M);
    gp_gemm<<<dim3(16, 2, 16), 256, 0, stream>>>(qs, M, obuf, stats + 1024);

    // conv2: stage raw obuf + quarter-concat bn+relu in LDS
    ga_gemm<256><<<dim3(32, 2, 16), 256, 0, stream>>>(
        obuf, 256, w2_b, 256,
        y2, y2, 1 << 28, 256, stats + 1536, stats + 1536, 0, 0,
        stats + 1024, gb0, bb0, gb1, bb1, ga2, ba2, ga3, ba3);

    r6_final<<<dim3(64, 4, 16), 256, 0, stream>>>(y2, ysc, stats + 1536, stats + 0,
                                                  g2, b2, gsc, bsc, (float*)d_out);
}